// Round 13
// baseline (69.535 us; speedup 1.0000x reference)
//
#include <hip/hip_runtime.h>
#include <cstdint>

typedef unsigned long long u64;
typedef unsigned int u32;

#define DIM    10000
#define NCLS   100
#define BATCH  4096
#define F4ROW  2500          // float4s per input row
#define NCH    40            // 256-dim chunks per row (chunk 39 partial)

// Bit order (identical for q and am): chunk C covers dims [C*256, C*256+256);
// word j of chunk C, bit i <- dim C*256 + 4i + j (ballot lane i, float4 elem j).
// apT2 layout: [wpair = 2C + (j>>1)][class], .x = word j=0/2, .y = word j=1/3.

// ---- PROBE: pure q read, exact m13 µbench shape (grid-stride float4) ----
// Measures this harness's q-read ceiling. acc >= 0 always (q in {0,1}) so the
// store never executes, but the compiler cannot prove that -> loads kept.
__global__ __launch_bounds__(256) void read_probe(const float* __restrict__ in,
                                                  float* __restrict__ sink) {
    const size_t n4     = (size_t)BATCH * DIM / 4;        // 10,240,000
    const size_t stride = (size_t)gridDim.x * 256;
    float acc = 0.f;
    for (size_t i = (size_t)blockIdx.x * 256 + threadIdx.x; i < n4; i += stride) {
        const float4 v = *(const float4*)(in + i * 4);
        acc += v.x + v.y + v.z + v.w;
    }
    if (acc < -1.0f) sink[threadIdx.x] = acc;             // never taken
}

// ---- pack am -> apT2 (VERBATIM rounds 7/10/11/12) ----
__global__ __launch_bounds__(256) void pack_a_t(const float* __restrict__ a,
                                                ulonglong2* __restrict__ apT2) {
    const int lane = threadIdx.x & 63;
    const int r    = blockIdx.x * 4 + (threadIdx.x >> 6);   // class 0..99
    const float* row = a + (size_t)r * DIM;
    for (int C = 0; C < NCH; ++C) {
        const int d0 = C * 256 + lane * 4;
        float4 v = make_float4(0.f, 0.f, 0.f, 0.f);
        if (d0 < DIM) v = *(const float4*)(row + d0);
        const u64 b0 = __ballot(v.x > 0.5f);
        const u64 b1 = __ballot(v.y > 0.5f);
        const u64 b2 = __ballot(v.z > 0.5f);
        const u64 b3 = __ballot(v.w > 0.5f);
        if (lane < 2) {
            ulonglong2 u;
            u.x = lane ? b2 : b0;
            u.y = lane ? b3 : b1;
            apT2[(size_t)(2 * C + lane) * NCLS + r] = u;    // wpair = 2C+lane
        }
    }
}

// ---- fused v4 (VERBATIM round 12 — experiment control) ----
__global__ __launch_bounds__(256) void fused_v4(const float* __restrict__ q,
                                                const ulonglong2* __restrict__ apT2,
                                                float* __restrict__ out) {
    __shared__ int part[4][4][128];                         // [wave][row][class]
    const int lane = threadIdx.x & 63;
    const int wv   = threadIdx.x >> 6;                      // 0..3 = chunk group
    const int r0   = blockIdx.x * 4;
    const int clsA = lane;
    const int clsB = 64 + (lane < NCLS - 64 ? lane : NCLS - 65);

    u32 accA[4] = {0, 0, 0, 0};
    u32 accB[4] = {0, 0, 0, 0};

    const int Cbeg = wv * 10;
    const int Cfull = (wv == 3) ? 39 : Cbeg + 10;           // chunk 39 handled apart

    for (int C = Cbeg; C < Cfull; ++C) {
        float4 v[4];
#pragma unroll
        for (int ri = 0; ri < 4; ++ri)
            v[ri] = *(const float4*)(q + (size_t)(r0 + ri) * DIM
                                       + (size_t)(C * 64 + lane) * 4);
        const ulonglong2* wp0 = apT2 + (size_t)(2 * C) * NCLS;
        const ulonglong2* wp1 = wp0 + NCLS;
        const ulonglong2 aA0 = wp0[clsA];
        const ulonglong2 aA1 = wp1[clsA];
        const ulonglong2 aB0 = wp0[clsB];
        const ulonglong2 aB1 = wp1[clsB];
#pragma unroll
        for (int ri = 0; ri < 4; ++ri) {
            const u64 b0 = __ballot(v[ri].x > 0.5f);
            const u64 b1 = __ballot(v[ri].y > 0.5f);
            const u64 b2 = __ballot(v[ri].z > 0.5f);
            const u64 b3 = __ballot(v[ri].w > 0.5f);
            accA[ri] += (u32)(__popcll(b0 ^ aA0.x) + __popcll(b1 ^ aA0.y) +
                              __popcll(b2 ^ aA1.x) + __popcll(b3 ^ aA1.y));
            accB[ri] += (u32)(__popcll(b0 ^ aB0.x) + __popcll(b1 ^ aB0.y) +
                              __popcll(b2 ^ aB1.x) + __popcll(b3 ^ aB1.y));
        }
    }

    if (wv == 3) {                                          // chunk 39: partial
        const int C    = 39;
        const int idx  = C * 64 + lane;
        const int lidx = idx < F4ROW ? idx : F4ROW - 1;
        const bool ok  = idx < F4ROW;
        const ulonglong2* wp0 = apT2 + (size_t)(2 * C) * NCLS;
        const ulonglong2* wp1 = wp0 + NCLS;
        const ulonglong2 aA0 = wp0[clsA];
        const ulonglong2 aA1 = wp1[clsA];
        const ulonglong2 aB0 = wp0[clsB];
        const ulonglong2 aB1 = wp1[clsB];
#pragma unroll
        for (int ri = 0; ri < 4; ++ri) {
            const float4 v = *(const float4*)(q + (size_t)(r0 + ri) * DIM
                                                + (size_t)lidx * 4);
            const u64 b0 = __ballot(ok && (v.x > 0.5f));
            const u64 b1 = __ballot(ok && (v.y > 0.5f));
            const u64 b2 = __ballot(ok && (v.z > 0.5f));
            const u64 b3 = __ballot(ok && (v.w > 0.5f));
            accA[ri] += (u32)(__popcll(b0 ^ aA0.x) + __popcll(b1 ^ aA0.y) +
                              __popcll(b2 ^ aA1.x) + __popcll(b3 ^ aA1.y));
            accB[ri] += (u32)(__popcll(b0 ^ aB0.x) + __popcll(b1 ^ aB0.y) +
                              __popcll(b2 ^ aB1.x) + __popcll(b3 ^ aB1.y));
        }
    }

#pragma unroll
    for (int ri = 0; ri < 4; ++ri) {
        part[wv][ri][lane] = (int)accA[ri];
        if (lane < NCLS - 64) part[wv][ri][64 + lane] = (int)accB[ri];
    }
    __syncthreads();

    const int tid = threadIdx.x;
#pragma unroll
    for (int o = tid; o < 4 * NCLS; o += 256) {
        const int ri  = o / NCLS;
        const int cls = o - ri * NCLS;
        const int s = part[0][ri][cls] + part[1][ri][cls] +
                      part[2][ri][cls] + part[3][ri][cls];
        out[(size_t)(r0 + ri) * NCLS + cls] = (float)(DIM - s);
    }
}

extern "C" void kernel_launch(void* const* d_in, const int* in_sizes, int n_in,
                              void* d_out, int out_size, void* d_ws, size_t ws_size,
                              hipStream_t stream) {
    const float* q = (const float*)d_in[0];   // [4096, 10000] f32 {0,1}
    const float* a = (const float*)d_in[1];   // [100, 10000]  f32 {0,1}
    float* out = (float*)d_out;               // [4096, 100]   f32

    // ws: apT2 (128,000 B) at 0; probe sink (unused, never written) at 1 MiB
    ulonglong2* apT2 = (ulonglong2*)d_ws;
    float*      sink = (float*)((char*)d_ws + (1u << 20));

    read_probe<<<2048, 256, 0, stream>>>(q, sink);          // INSTRUMENTATION
    pack_a_t<<<25, 256, 0, stream>>>(a, apT2);
    fused_v4<<<BATCH / 4, 256, 0, stream>>>(q, apT2, out);
}

// Round 14
// 46.962 us; speedup vs baseline: 1.4807x; 1.4807x over previous
//
#include <hip/hip_runtime.h>
#include <cstdint>

typedef unsigned long long u64;
typedef unsigned int u32;

#define DIM    10000
#define NCLS   100
#define BATCH  4096
#define F4ROW  2500          // float4s per input row
#define NCH    40            // 256-dim chunks per row (chunk 39 partial)
#define RPB    16            // rows per block
#define CPW    5             // chunks per wave (8 waves x 5 = 40)

// Bit order (identical for q and am): chunk C covers dims [C*256, C*256+256);
// word j of chunk C, bit i <- dim C*256 + 4i + j (ballot lane i, float4 elem j).
// apT2 layout: [wpair = 2C + s][class]; s=0 holds (b0,b1), s=1 holds (b2,b3).
// Pad dims (>= DIM) give 0-bits on BOTH operands -> XOR contributes nothing.

// ---- pack am -> apT2 (VERBATIM rounds 7/10/11/12) ----
__global__ __launch_bounds__(256) void pack_a_t(const float* __restrict__ a,
                                                ulonglong2* __restrict__ apT2) {
    const int lane = threadIdx.x & 63;
    const int r    = blockIdx.x * 4 + (threadIdx.x >> 6);   // class 0..99
    const float* row = a + (size_t)r * DIM;
    for (int C = 0; C < NCH; ++C) {
        const int d0 = C * 256 + lane * 4;
        float4 v = make_float4(0.f, 0.f, 0.f, 0.f);
        if (d0 < DIM) v = *(const float4*)(row + d0);
        const u64 b0 = __ballot(v.x > 0.5f);
        const u64 b1 = __ballot(v.y > 0.5f);
        const u64 b2 = __ballot(v.z > 0.5f);
        const u64 b3 = __ballot(v.w > 0.5f);
        if (lane < 2) {
            ulonglong2 u;
            u.x = lane ? b2 : b0;
            u.y = lane ? b3 : b1;
            apT2[(size_t)(2 * C + lane) * NCLS + r] = u;    // wpair = 2C+lane
        }
    }
}

// ---- fused v5: register-resident ap; q loop = pure stream + VALU ----
// block = 512 threads (8 waves); wave w owns chunks [5w, 5w+5) for ALL 16 rows.
// ap for those chunks lives in 80 statically-indexed VGPRs (loaded once).
// grid = BATCH/RPB = 256 blocks = 1 block/CU.
__global__ __launch_bounds__(512) void fused_v5(const float* __restrict__ q,
                                                const ulonglong2* __restrict__ apT2,
                                                float* __restrict__ out) {
    __shared__ int part[8][RPB][NCLS];                      // 51,200 B
    const int lane = threadIdx.x & 63;
    const int wv   = threadIdx.x >> 6;                      // 0..7
    const int r0   = blockIdx.x * RPB;
    const int Cb   = wv * CPW;                              // first owned chunk
    const int clsA = lane;                                  // always < NCLS
    const int clsB = 64 + (lane < NCLS - 64 ? lane : NCLS - 65);

    // ---- preload ap slice into registers (static indexing only) ----
    ulonglong2 apA[CPW][2], apB[CPW][2];
#pragma unroll
    for (int c = 0; c < CPW; ++c) {
#pragma unroll
        for (int s = 0; s < 2; ++s) {
            const size_t wp = (size_t)(2 * (Cb + c) + s) * NCLS;
            apA[c][s] = apT2[wp + clsA];                    // coalesced
            apB[c][s] = apT2[wp + clsB];
        }
    }

    // ---- stream q rows: 16 rows x 5 chunks, 1 load + ~46 VALU each ----
    for (int ri = 0; ri < RPB; ++ri) {
        const float* row = q + (size_t)(r0 + ri) * DIM;
        u32 accA = 0, accB = 0;
#pragma unroll
        for (int c = 0; c < CPW; ++c) {
            const int idx  = (Cb + c) * 64 + lane;          // f4 index
            const int lidx = idx < F4ROW ? idx : F4ROW - 1; // clamp (chunk 39)
            const bool ok  = idx < F4ROW;
            const float4 v = *(const float4*)(row + (size_t)lidx * 4);
            const u64 b0 = __ballot(ok && (v.x > 0.5f));    // wave-uniform
            const u64 b1 = __ballot(ok && (v.y > 0.5f));
            const u64 b2 = __ballot(ok && (v.z > 0.5f));
            const u64 b3 = __ballot(ok && (v.w > 0.5f));
            accA += (u32)(__popcll(b0 ^ apA[c][0].x) + __popcll(b1 ^ apA[c][0].y) +
                          __popcll(b2 ^ apA[c][1].x) + __popcll(b3 ^ apA[c][1].y));
            accB += (u32)(__popcll(b0 ^ apB[c][0].x) + __popcll(b1 ^ apB[c][0].y) +
                          __popcll(b2 ^ apB[c][1].x) + __popcll(b3 ^ apB[c][1].y));
        }
        part[wv][ri][lane] = (int)accA;
        if (lane < NCLS - 64) part[wv][ri][64 + lane] = (int)accB;
    }
    __syncthreads();

    // ---- 8-way reduce + write (coalesced) ----
    for (int o = threadIdx.x; o < RPB * NCLS; o += 512) {
        const int ri  = o / NCLS;
        const int cls = o - ri * NCLS;
        int s = 0;
#pragma unroll
        for (int w = 0; w < 8; ++w) s += part[w][ri][cls];
        out[(size_t)(r0 + ri) * NCLS + cls] = (float)(DIM - s);
    }
}

extern "C" void kernel_launch(void* const* d_in, const int* in_sizes, int n_in,
                              void* d_out, int out_size, void* d_ws, size_t ws_size,
                              hipStream_t stream) {
    const float* q = (const float*)d_in[0];   // [4096, 10000] f32 {0,1}
    const float* a = (const float*)d_in[1];   // [100, 10000]  f32 {0,1}
    float* out = (float*)d_out;               // [4096, 100]   f32

    // ws: apT2 only (80 wpairs * 100 classes * 16 B = 128,000 B)
    ulonglong2* apT2 = (ulonglong2*)d_ws;

    pack_a_t<<<25, 256, 0, stream>>>(a, apT2);
    fused_v5<<<BATCH / RPB, 512, 0, stream>>>(q, apT2, out);
}